// Round 15
// baseline (397.919 us; speedup 1.0000x reference)
//
#include <hip/hip_runtime.h>

#define T_ 512
#define B_ 2048
#define NB_ 8                 // batches per block; grid = B_/NB_ = 256 = 1 block/CU
#define TANH_K (-2.8853900817779268f)   // -2*log2(e)

// LDS layout, batch-innermost for bank-conflict freedom.
// Per (buf,t) slot = 160 B:  A[8 batches]x8B | C[8]x8B | B[8]x4B
//   A = f16 cols 0-3 (dir0 h0..h3), B.lo = col4 (dir0 h4), B.hi = col5 (dir1 h0),
//   C = cols 6-9 (dir1 h1..h4).
#define BUFOFF 81920
#define SLOT   160

// DPP ctrl encodings (gfx9/CDNA)
#define DPP_ROW_ROR8        0x128   // lane^8  within 16-lane row
#define DPP_ROW_MIRROR      0x140   // lane^15 within 16-lane row
#define DPP_ROW_HALF_MIRROR 0x141   // lane^7  within 16-lane row

// NOTE (r10-r12 post-mortem): any use of v_pk_fma_f32 / packed f32 VOP3P in the
// recurrence produced deterministic wrong results. Scalar VALU producers only.

__device__ __forceinline__ float sig2h(float y) {
  // 2 / (1 + exp2(y)); caller pre-scales y.
  return __builtin_amdgcn_rcpf(fmaf(__builtin_amdgcn_exp2f(y), 0.5f, 0.5f));
}

template<int CTRL>
__device__ __forceinline__ float dppf(float v) {
  return __int_as_float(__builtin_amdgcn_mov_dpp(__float_as_int(v), CTRL, 0xF, 0xF, true));
}

typedef __fp16 fp16x2 __attribute__((ext_vector_type(2)));

__device__ __forceinline__ unsigned pkrtz(float a, float b) {  // 2xf32 -> packed f16
  union { fp16x2 h; unsigned u; } cv;
  cv.h = __builtin_amdgcn_cvt_pkrtz(a, b);
  return cv.u;
}

__device__ __forceinline__ float fdot2(unsigned x, unsigned w, float acc) {
  float r;
  asm("v_dot2_f32_f16 %0, %1, %2, %3" : "=v"(r) : "v"(x), "v"(w), "v"(acc));
  return r;
}

struct Row5 { uint2 a; unsigned b; uint2 c; };
struct Pre2 { float a, b; };
struct WS {
  unsigned wpA[5], wpB[5];     // packed f16 input-weight pairs (km-scaled)
  float wsA[5], wsB[5];        // slot-permuted recurrent weights (km-scaled)
  float bbA, bbB;              // km-scaled biases
};

__device__ __forceinline__ Row5 ld_row(const unsigned char* ldsb, int pA, int pB) {
  Row5 r;
  r.a = *(const uint2*)(ldsb + pA);        // ds_read_b64, offset 0
  r.c = *(const uint2*)(ldsb + pA + 64);   // ds_read_b64, offset 64 (immediate)
  r.b = *(const unsigned*)(ldsb + pB);     // ds_read_b32
  return r;
}

// Dual input projection (standalone, used in prologue/tails).
__device__ __forceinline__ Pre2 proj_dual(const Row5& r, const WS& W) {
  float a = fdot2(r.a.x, W.wpA[0], W.bbA);
  a = fdot2(r.a.y, W.wpA[1], a);
  a = fdot2(r.b,   W.wpA[2], a);
  a = fdot2(r.c.x, W.wpA[3], a);
  a = fdot2(r.c.y, W.wpA[4], a);
  float b = fdot2(r.a.x, W.wpB[0], W.bbB);
  b = fdot2(r.a.y, W.wpB[1], b);
  b = fdot2(r.b,   W.wpB[2], b);
  b = fdot2(r.c.x, W.wpB[3], b);
  b = fdot2(r.c.y, W.wpB[4], b);
  Pre2 o; o.a = a; o.b = b; return o;
}

// Plain recurrent step (r13-proven; used for layer-0, tails, layer-4 bwd).
__device__ __forceinline__ void recur_dual(float preA, float preB, const WS& W,
    float vm, float va,
    float& c, float& c4, float& h0s, float& h1s, float& h2s, float& h3s, float& h4)
{
  const float a0 = fmaf(W.wsA[1], h1s, fmaf(W.wsA[0], h0s, preA));
  const float a1 = fmaf(W.wsA[4], h4,  fmaf(W.wsA[3], h3s, W.wsA[2] * h2s));
  const float b0 = fmaf(W.wsB[1], h1s, fmaf(W.wsB[0], h0s, preB));
  const float b1 = fmaf(W.wsB[4], h4,  fmaf(W.wsB[3], h3s, W.wsB[2] * h2s));
  const float s2A = sig2h(a0 + a1);
  const float s2B = sig2h(b0 + b1);
  const float vA = fmaf(s2A, vm, va);
  const float vB = fmaf(s2B, vm, va);
  const float ivA = dppf<0x00>(vA), fvA = dppf<0x55>(vA), gvA = dppf<0xAA>(vA), ovA = dppf<0xFF>(vA);
  const float ivB = dppf<0x00>(vB), fvB = dppf<0x55>(vB), gvB = dppf<0xAA>(vB), ovB = dppf<0xFF>(vB);
  c  = fmaf(fvA, c,  ivA * gvA);
  c4 = fmaf(fvB, c4, ivB * gvB);
  const float t2A = sig2h(c * TANH_K);
  const float t2B = sig2h(c4 * TANH_K);
  const float h = fmaf(t2A, ovA, -ovA);
  h4            = fmaf(t2B, ovB, -ovB);
  h0s = h;
  h1s = dppf<DPP_ROW_HALF_MIRROR>(h);
  h2s = dppf<DPP_ROW_ROR8>(h);
  h3s = dppf<DPP_ROW_MIRROR>(h);
}

// Fused + SCHEDULE-PINNED step: recurrence for step t with the projection of
// row nr (consumed 4 steps later) placed in the transcendental latency shadows.
// sched_barrier(0) fences pin the interleave against the MachineScheduler
// (r14's unfenced version was re-clustered; this enforces it). Pure VALU/trans
// inside the fences — no memory ops, so no waitcnt-pinning hazard (m141).
// Arithmetic identical to recur_dual + proj_dual.
__device__ __forceinline__ void recur_fused(float preA, float preB, const WS& W,
    float vm, float va, const Row5& nr, Pre2& preout,
    float& c, float& c4, float& h0s, float& h1s, float& h2s, float& h3s, float& h4)
{
#define SB() __builtin_amdgcn_sched_barrier(0)
  // P1: gate pre-activations (serial dep on previous step's h state)
  const float a0 = fmaf(W.wsA[1], h1s, fmaf(W.wsA[0], h0s, preA));
  const float a1 = fmaf(W.wsA[4], h4,  fmaf(W.wsA[3], h3s, W.wsA[2] * h2s));
  const float b0 = fmaf(W.wsB[1], h1s, fmaf(W.wsB[0], h0s, preB));
  const float b1 = fmaf(W.wsB[4], h4,  fmaf(W.wsB[3], h3s, W.wsB[2] * h2s));
  const float accA = a0 + a1;
  const float accB = b0 + b1;
  SB();
  // F1: independent projection ops cover the acc->exp2 operand latency
  float pa = fdot2(nr.a.x, W.wpA[0], W.bbA);
  float pb = fdot2(nr.a.x, W.wpB[0], W.bbB);
  SB();
  const float eA = __builtin_amdgcn_exp2f(accA);
  const float eB = __builtin_amdgcn_exp2f(accB);
  SB();
  // F2: cover exp2 latency
  pa = fdot2(nr.a.y, W.wpA[1], pa);
  pb = fdot2(nr.a.y, W.wpB[1], pb);
  pa = fdot2(nr.b,   W.wpA[2], pa);
  pb = fdot2(nr.b,   W.wpB[2], pb);
  SB();
  const float s2A = __builtin_amdgcn_rcpf(fmaf(eA, 0.5f, 0.5f));
  const float s2B = __builtin_amdgcn_rcpf(fmaf(eB, 0.5f, 0.5f));
  SB();
  // F3: cover rcp latency
  pa = fdot2(nr.c.x, W.wpA[3], pa);
  pb = fdot2(nr.c.x, W.wpB[3], pb);
  SB();
  const float vA = fmaf(s2A, vm, va);
  const float vB = fmaf(s2B, vm, va);
  const float ivA = dppf<0x00>(vA), fvA = dppf<0x55>(vA), gvA = dppf<0xAA>(vA), ovA = dppf<0xFF>(vA);
  const float ivB = dppf<0x00>(vB), fvB = dppf<0x55>(vB), gvB = dppf<0xAA>(vB), ovB = dppf<0xFF>(vB);
  c  = fmaf(fvA, c,  ivA * gvA);
  c4 = fmaf(fvB, c4, ivB * gvB);
  const float eCA = __builtin_amdgcn_exp2f(c * TANH_K);
  const float eCB = __builtin_amdgcn_exp2f(c4 * TANH_K);
  SB();
  // F4: cover tanh-exp2 latency
  pa = fdot2(nr.c.y, W.wpA[4], pa);
  pb = fdot2(nr.c.y, W.wpB[4], pb);
  SB();
  const float t2A = __builtin_amdgcn_rcpf(fmaf(eCA, 0.5f, 0.5f));
  const float t2B = __builtin_amdgcn_rcpf(fmaf(eCB, 0.5f, 0.5f));
  SB();
  preout.a = pa; preout.b = pb;
  const float h = fmaf(t2A, ovA, -ovA);
  h4            = fmaf(t2B, ovB, -ovB);
  h0s = h;
  h1s = dppf<DPP_ROW_HALF_MIRROR>(h);
  h2s = dppf<DPP_ROW_ROR8>(h);
  h3s = dppf<DPP_ROW_MIRROR>(h);
#undef SB
}

template<int DD>
__device__ __forceinline__ void emit_row(unsigned char* ldsb, int dpA, int dpB,
    float h0s, float h1s, float h2s, float h3s, float h4) {
  if constexpr (DD) {
    uint2 pr; pr.x = pkrtz(h1s, h2s); pr.y = pkrtz(h3s, h4);
    *(uint2*)(ldsb + dpA + 64) = pr;                                  // C pair
    *(unsigned short*)(ldsb + dpB + 2) = (unsigned short)pkrtz(h0s, h0s); // B.hi
  } else {
    uint2 pr; pr.x = pkrtz(h0s, h1s); pr.y = pkrtz(h2s, h3s);
    *(uint2*)(ldsb + dpA) = pr;                                       // A pair
    *(unsigned short*)(ldsb + dpB) = (unsigned short)pkrtz(h4, h4);   // B.lo
  }
}

// LDS-input scan (layers 1..4), 4-slot fused software pipeline.
template<int DD, bool STORE>
__device__ __forceinline__ void scan_lds(unsigned char* ldsb, int pA, int pB,
    int dpA, int dpB, bool doStore, const WS& W, float vm, float va,
    float& c, float& c4, float& h0s, float& h1s, float& h2s, float& h3s, float& h4)
{
  constexpr int s = DD ? -SLOT : SLOT;
  Row5 p_[4]; Pre2 pre[4];
  #pragma unroll
  for (int k = 0; k < 4; ++k) { p_[k] = ld_row(ldsb, pA, pB); pA += s; pB += s; }
  #pragma unroll
  for (int k = 0; k < 4; ++k) pre[k] = proj_dual(p_[k], W);
  #pragma unroll
  for (int k = 0; k < 4; ++k) { p_[k] = ld_row(ldsb, pA, pB); pA += s; pB += s; }
  c = 0.f; c4 = 0.f; h0s = h1s = h2s = h3s = h4 = 0.f;
  for (int tt = 0; tt + 8 < T_; tt += 4) {
    #pragma unroll
    for (int j = 0; j < 4; ++j) {
      Pre2 np;
      recur_fused(pre[j].a, pre[j].b, W, vm, va, p_[j], np,
                  c, c4, h0s, h1s, h2s, h3s, h4);
      if constexpr (STORE) {
        if (doStore) emit_row<DD>(ldsb, dpA, dpB, h0s, h1s, h2s, h3s, h4);
        dpA += s; dpB += s;
      }
      pre[j] = np;
      p_[j] = ld_row(ldsb, pA, pB); pA += s; pB += s;
    }
  }
  #pragma unroll
  for (int j = 0; j < 4; ++j) {     // steps T-8..T-5: refill pre from last rows
    Pre2 np;
    recur_fused(pre[j].a, pre[j].b, W, vm, va, p_[j], np,
                c, c4, h0s, h1s, h2s, h3s, h4);
    if constexpr (STORE) {
      if (doStore) emit_row<DD>(ldsb, dpA, dpB, h0s, h1s, h2s, h3s, h4);
      dpA += s; dpB += s;
    }
    pre[j] = np;
  }
  #pragma unroll
  for (int j = 0; j < 4; ++j) {     // steps T-4..T-1: consume only
    recur_dual(pre[j].a, pre[j].b, W, vm, va, c, c4, h0s, h1s, h2s, h3s, h4);
    if constexpr (STORE) {
      if (doStore) emit_row<DD>(ldsb, dpA, dpB, h0s, h1s, h2s, h3s, h4);
      dpA += s; dpB += s;
    }
  }
}

// Layer-0 scan: f32 global input (width 2), packed to f16 + dot2. 8-deep prefetch.
template<int DD>
__device__ __forceinline__ void scan0(const float* src, unsigned char* ldsb,
    int dpA, int dpB, bool doStore, const WS& W, float vm, float va)
{
  constexpr int sstep = DD ? -2 : 2;
  constexpr int s = DD ? -SLOT : SLOT;
  float2 p_[8]; Pre2 pre[8];
  #pragma unroll
  for (int k = 0; k < 8; ++k) p_[k] = *(const float2*)(src + k * sstep);
  #pragma unroll
  for (int k = 0; k < 8; ++k) {
    const unsigned xp = pkrtz(p_[k].x, p_[k].y);
    pre[k].a = fdot2(xp, W.wpA[0], W.bbA);
    pre[k].b = fdot2(xp, W.wpB[0], W.bbB);
  }
  #pragma unroll
  for (int k = 0; k < 8; ++k) p_[k] = *(const float2*)(src + (8 + k) * sstep);
  const float* lp = src + 16 * sstep;
  float c = 0.f, c4 = 0.f, h0s = 0.f, h1s = 0.f, h2s = 0.f, h3s = 0.f, h4 = 0.f;
  for (int tt = 0; tt + 16 < T_; tt += 8) {
    #pragma unroll
    for (int j = 0; j < 8; ++j) {
      recur_dual(pre[j].a, pre[j].b, W, vm, va, c, c4, h0s, h1s, h2s, h3s, h4);
      if (doStore) emit_row<DD>(ldsb, dpA, dpB, h0s, h1s, h2s, h3s, h4);
      dpA += s; dpB += s;
      const unsigned xp = pkrtz(p_[j].x, p_[j].y);
      pre[j].a = fdot2(xp, W.wpA[0], W.bbA);
      pre[j].b = fdot2(xp, W.wpB[0], W.bbB);
      p_[j] = *(const float2*)lp; lp += sstep;
    }
  }
  #pragma unroll
  for (int j = 0; j < 8; ++j) {
    recur_dual(pre[j].a, pre[j].b, W, vm, va, c, c4, h0s, h1s, h2s, h3s, h4);
    if (doStore) emit_row<DD>(ldsb, dpA, dpB, h0s, h1s, h2s, h3s, h4);
    dpA += s; dpB += s;
    const unsigned xp = pkrtz(p_[j].x, p_[j].y);
    pre[j].a = fdot2(xp, W.wpA[0], W.bbA);
    pre[j].b = fdot2(xp, W.wpB[0], W.bbB);
  }
  #pragma unroll
  for (int j = 0; j < 8; ++j) {
    recur_dual(pre[j].a, pre[j].b, W, vm, va, c, c4, h0s, h1s, h2s, h3s, h4);
    if (doStore) emit_row<DD>(ldsb, dpA, dpB, h0s, h1s, h2s, h3s, h4);
    dpA += s; dpB += s;
  }
}

__device__ __forceinline__ void load_rec(WS& W, const float* Whp, const float* bp,
    int rowA, int rowB, int p, int i1, int i2, int i3, float km) {
  W.wsA[0] = Whp[rowA*5+p]*km;  W.wsA[1] = Whp[rowA*5+i1]*km; W.wsA[2] = Whp[rowA*5+i2]*km;
  W.wsA[3] = Whp[rowA*5+i3]*km; W.wsA[4] = Whp[rowA*5+4]*km;
  W.wsB[0] = Whp[rowB*5+p]*km;  W.wsB[1] = Whp[rowB*5+i1]*km; W.wsB[2] = Whp[rowB*5+i2]*km;
  W.wsB[3] = Whp[rowB*5+i3]*km; W.wsB[4] = Whp[rowB*5+4]*km;
  W.bbA = bp[rowA]*km; W.bbB = bp[rowB]*km;
}

__global__ __launch_bounds__(256) void lstm_all(
    const float* __restrict__ x, const float* __restrict__ Wih0,
    const float* __restrict__ Wih, const float* __restrict__ Whh,
    const float* __restrict__ bias, const float* __restrict__ Wfc,
    const float* __restrict__ bfc, float* __restrict__ out)
{
  __shared__ __align__(16) unsigned char ldsb[163840];   // gfx950 LDS max

  const int tid  = threadIdx.x;
  const int lane = tid & 63;
  const int wave = tid >> 6;
  const int cw   = lane >> 4;          // chain within wave: 0..3
  const int sub  = lane & 15;
  const int p    = sub >> 2;           // hidden unit (quad) 0..3
  const int g    = sub & 3;            // gate 0=i,1=f,2=g,3=o
  const int rowA = g * 5 + p;
  const int rowB = g * 5 + 4;
  const int dd   = wave & 1;           // direction, WAVE-UNIFORM
  const int blb  = cw + (wave >> 1) * 4;   // block-local batch 0..7
  const int babs = blockIdx.x * NB_ + blb;

  const int i1 = p ^ 1, i2 = p ^ 2, i3 = p ^ 3;

  const float LOG2E = 1.4426950408889634f;
  const float km = (g == 2) ? (-2.0f * LOG2E) : (-LOG2E);
  const float vm = (g == 2) ? 1.0f : 0.5f;
  const float va = (g == 2) ? -1.0f : 0.0f;

  const bool doStore = (sub == 0);
  const int t0 = dd ? (T_ - 1) : 0;
  const int slotA = blb * 8;
  const int slotB = 128 + blb * 4;

  WS W;
  float c, c4, h0s, h1s, h2s, h3s, h4;

  // ---------------- layer 0 (f32 x, width 2) -> buf0 ----------------
  {
    const float* W0 = Wih0 + (size_t)dd * 20 * 2;
    W.wpA[0] = pkrtz(W0[rowA*2+0]*km, W0[rowA*2+1]*km);
    W.wpB[0] = pkrtz(W0[rowB*2+0]*km, W0[rowB*2+1]*km);
    load_rec(W, Whh + (size_t)dd * 20 * 5, bias + (size_t)dd * 20,
             rowA, rowB, p, i1, i2, i3, km);
    const int dpA = t0 * SLOT + slotA;            // buf0
    const int dpB = t0 * SLOT + slotB;
    const float* src0 = x + ((size_t)babs * T_ + t0) * 2;
    if (dd == 0) scan0<0>(src0, ldsb, dpA, dpB, doStore, W, vm, va);
    else         scan0<1>(src0, ldsb, dpA, dpB, doStore, W, vm, va);
  }
  __syncthreads();

  // ---------------- layers 1..3 ----------------
  for (int l = 1; l < 4; ++l) {
    const float* Wip = Wih + ((size_t)(l - 1) * 2 + dd) * 20 * 10;
    #pragma unroll
    for (int k = 0; k < 5; ++k) {
      W.wpA[k] = pkrtz(Wip[rowA*10+2*k]*km, Wip[rowA*10+2*k+1]*km);
      W.wpB[k] = pkrtz(Wip[rowB*10+2*k]*km, Wip[rowB*10+2*k+1]*km);
    }
    load_rec(W, Whh + ((size_t)l * 2 + dd) * 20 * 5, bias + ((size_t)l * 2 + dd) * 20,
             rowA, rowB, p, i1, i2, i3, km);
    const int sbuf = (l + 1) & 1, dbuf = l & 1;           // L1:0->1 L2:1->0 L3:0->1
    const int pA  = sbuf * BUFOFF + t0 * SLOT + slotA;
    const int pB  = sbuf * BUFOFF + t0 * SLOT + slotB;
    const int dpA = dbuf * BUFOFF + t0 * SLOT + slotA;
    const int dpB = dbuf * BUFOFF + t0 * SLOT + slotB;
    if (dd == 0) scan_lds<0, true>(ldsb, pA, pB, dpA, dpB, doStore, W, vm, va,
                                   c, c4, h0s, h1s, h2s, h3s, h4);
    else         scan_lds<1, true>(ldsb, pA, pB, dpA, dpB, doStore, W, vm, va,
                                   c, c4, h0s, h1s, h2s, h3s, h4);
    __syncthreads();
  }

  // ---------------- layer 4 (reads buf1): fwd full scan, bwd 1 step ----------------
  {
    const float* Wip = Wih + ((size_t)3 * 2 + dd) * 20 * 10;
    #pragma unroll
    for (int k = 0; k < 5; ++k) {
      W.wpA[k] = pkrtz(Wip[rowA*10+2*k]*km, Wip[rowA*10+2*k+1]*km);
      W.wpB[k] = pkrtz(Wip[rowB*10+2*k]*km, Wip[rowB*10+2*k+1]*km);
    }
    load_rec(W, Whh + ((size_t)4 * 2 + dd) * 20 * 5, bias + ((size_t)4 * 2 + dd) * 20,
             rowA, rowB, p, i1, i2, i3, km);

    if (dd == 0) {
      const int pA = BUFOFF + slotA;                       // forward from t=0
      const int pB = BUFOFF + slotB;
      scan_lds<0, false>(ldsb, pA, pB, 0, 0, false, W, vm, va,
                         c, c4, h0s, h1s, h2s, h3s, h4);
    } else {
      const int pA = BUFOFF + (T_ - 1) * SLOT + slotA;
      const int pB = BUFOFF + (T_ - 1) * SLOT + slotB;
      Row5 r = ld_row(ldsb, pA, pB);
      Pre2 pr = proj_dual(r, W);
      c = 0.f; c4 = 0.f; h0s = h1s = h2s = h3s = h4 = 0.f;
      recur_dual(pr.a, pr.b, W, vm, va, c, c4, h0s, h1s, h2s, h3s, h4);
    }
  }
  // hlast overlays the dead buf0 head (80 floats = 320 B).
  {
    float* hl = (float*)ldsb;
    if (doStore) {
      const int base = (blb * 2 + dd) * 5;
      hl[base + 0] = h0s; hl[base + 1] = h1s; hl[base + 2] = h2s;
      hl[base + 3] = h3s; hl[base + 4] = h4;
    }
  }
  __syncthreads();

  // ---------------- fused FC: out[b] = hlast[b] @ Wfc^T + bfc ----------------
  if (tid < 16) {
    const int bl = tid >> 1, o = tid & 1;
    const float* hl = (const float*)ldsb;
    const int gb = blockIdx.x * NB_ + bl;
    float a = bfc[o];
    #pragma unroll
    for (int u = 0; u < 5; ++u) a = fmaf(hl[(bl*2+0)*5 + u], Wfc[o * 10 + u], a);
    #pragma unroll
    for (int u = 0; u < 5; ++u) a = fmaf(hl[(bl*2+1)*5 + u], Wfc[o * 10 + 5 + u], a);
    out[gb * 2 + o] = a;
  }
}

extern "C" void kernel_launch(void* const* d_in, const int* in_sizes, int n_in,
                              void* d_out, int out_size, void* d_ws, size_t ws_size,
                              hipStream_t stream) {
  (void)in_sizes; (void)n_in; (void)out_size; (void)d_ws; (void)ws_size;
  const float* x    = (const float*)d_in[0];
  const float* Wih0 = (const float*)d_in[1];
  const float* Wih  = (const float*)d_in[2];
  const float* Whh  = (const float*)d_in[3];
  const float* bias = (const float*)d_in[4];
  const float* Wfc  = (const float*)d_in[5];
  const float* bfc  = (const float*)d_in[6];
  float* out = (float*)d_out;

  dim3 grid(B_ / NB_);   // 256 blocks, 1 per CU
  dim3 block(256);
  lstm_all<<<grid, block, 0, stream>>>(x, Wih0, Wih, Whh, bias, Wfc, bfc, out);
}

// Round 16
// 385.798 us; speedup vs baseline: 1.0314x; 1.0314x over previous
//
#include <hip/hip_runtime.h>

#define T_ 512
#define B_ 2048
#define NB_ 8                 // batches per block; grid = B_/NB_ = 256 = 1 block/CU
#define TANH_K (-2.8853900817779268f)   // -2*log2(e)

// LDS layout, batch-innermost for bank-conflict freedom.
// Per (buf,t) slot = 160 B:  A[8 batches]x8B | C[8]x8B | B[8]x4B
//   A = f16 cols 0-3 (dir0 h0..h3), B.lo = col4 (dir0 h4), B.hi = col5 (dir1 h0),
//   C = cols 6-9 (dir1 h1..h4).
#define BUFOFF 81920
#define SLOT   160

// DPP ctrl encodings (gfx9/CDNA)
#define DPP_ROW_ROR8        0x128   // lane^8  within 16-lane row
#define DPP_ROW_MIRROR      0x140   // lane^15 within 16-lane row
#define DPP_ROW_HALF_MIRROR 0x141   // lane^7  within 16-lane row

// NOTE (r10-r12 post-mortem): any use of v_pk_fma_f32 / packed f32 VOP3P in the
// recurrence produced deterministic wrong results. Scalar VALU producers only.
// NOTE (r14/r15): source-interleave and sched_barrier pinning both neutral —
// the residual ~160cyc/step is transcendental-unit issue (16 cyc per trans op),
// not schedulable bubbles. Optimize by REMOVING trans ops.

__device__ __forceinline__ float sig2h(float y) {
  // 2 / (1 + exp2(y)); caller pre-scales y.
  return __builtin_amdgcn_rcpf(fmaf(__builtin_amdgcn_exp2f(y), 0.5f, 0.5f));
}

template<int CTRL>
__device__ __forceinline__ float dppf(float v) {
  return __int_as_float(__builtin_amdgcn_mov_dpp(__float_as_int(v), CTRL, 0xF, 0xF, true));
}

typedef __fp16 fp16x2 __attribute__((ext_vector_type(2)));

__device__ __forceinline__ unsigned pkrtz(float a, float b) {  // 2xf32 -> packed f16
  union { fp16x2 h; unsigned u; } cv;
  cv.h = __builtin_amdgcn_cvt_pkrtz(a, b);
  return cv.u;
}

__device__ __forceinline__ float fdot2(unsigned x, unsigned w, float acc) {
  // D = x.f16[0]*w.f16[0] + x.f16[1]*w.f16[1] + acc   (v_dot2_f32_f16)
  float r;
  asm("v_dot2_f32_f16 %0, %1, %2, %3" : "=v"(r) : "v"(x), "v"(w), "v"(acc));
  return r;
}

struct Row5 { uint2 a; unsigned b; uint2 c; };
struct Pre2 { float a, b; };
struct WS {
  unsigned wpA[5], wpB[5];     // packed f16 input-weight pairs (km-scaled)
  float wsA[5], wsB[5];        // slot-permuted recurrent weights (km-scaled)
  float bbA, bbB;              // km-scaled biases
};

__device__ __forceinline__ Row5 ld_row(const unsigned char* ldsb, int pA, int pB) {
  Row5 r;
  r.a = *(const uint2*)(ldsb + pA);        // ds_read_b64, offset 0
  r.c = *(const uint2*)(ldsb + pA + 64);   // ds_read_b64, offset 64 (immediate)
  r.b = *(const unsigned*)(ldsb + pB);     // ds_read_b32
  return r;
}

// Dual input projection via f16 dot2.
__device__ __forceinline__ Pre2 proj_dual(const Row5& r, const WS& W) {
  float a = fdot2(r.a.x, W.wpA[0], W.bbA);
  a = fdot2(r.a.y, W.wpA[1], a);
  a = fdot2(r.b,   W.wpA[2], a);
  a = fdot2(r.c.x, W.wpA[3], a);
  a = fdot2(r.c.y, W.wpA[4], a);
  float b = fdot2(r.a.x, W.wpB[0], W.bbB);
  b = fdot2(r.a.y, W.wpB[1], b);
  b = fdot2(r.b,   W.wpB[2], b);
  b = fdot2(r.c.x, W.wpB[3], b);
  b = fdot2(r.c.y, W.wpB[4], b);
  Pre2 o; o.a = a; o.b = b; return o;
}

// One recurrent step for a 16-lane chain. Lane = 4p+g: row A = gate g of unit p,
// row B = gate g of unit 4 (redundant/identical in every quad).
// TANH LANE-SPLIT (r16): c is quad-uniform and c4 group-uniform, so the tanh
// trans pair is computed once: lanes with (g&2)==0 evaluate sig2h(c*K), lanes
// with (g&2)!=0 evaluate sig2h(c4*K); quad_perm broadcasts recover both.
// Bit-identical to computing both on every lane. csel4 = (g&2) as bool.
__device__ __forceinline__ void recur_dual(float preA, float preB, const WS& W,
    float vm, float va, bool csel4,
    float& c, float& c4, float& h0s, float& h1s, float& h2s, float& h3s, float& h4)
{
  const float a0 = fmaf(W.wsA[1], h1s, fmaf(W.wsA[0], h0s, preA));
  const float a1 = fmaf(W.wsA[4], h4,  fmaf(W.wsA[3], h3s, W.wsA[2] * h2s));
  const float b0 = fmaf(W.wsB[1], h1s, fmaf(W.wsB[0], h0s, preB));
  const float b1 = fmaf(W.wsB[4], h4,  fmaf(W.wsB[3], h3s, W.wsB[2] * h2s));
  const float s2A = sig2h(a0 + a1);               // 2*sigmoid
  const float s2B = sig2h(b0 + b1);
  const float vA = fmaf(s2A, vm, va);             // sigmoid (vm=.5), or tanh = s2-1
  const float vB = fmaf(s2B, vm, va);
  const float ivA = dppf<0x00>(vA), fvA = dppf<0x55>(vA), gvA = dppf<0xAA>(vA), ovA = dppf<0xFF>(vA);
  const float ivB = dppf<0x00>(vB), fvB = dppf<0x55>(vB), gvB = dppf<0xAA>(vB), ovB = dppf<0xFF>(vB);
  c  = fmaf(fvA, c,  ivA * gvA);
  c4 = fmaf(fvB, c4, ivB * gvB);
  const float csel = csel4 ? c4 : c;              // lane-split tanh input
  const float t2 = sig2h(csel * TANH_K);          // ONE trans pair (was two)
  const float t2A = dppf<0x00>(t2);               // lane g=0: c-version
  const float t2B = dppf<0xAA>(t2);               // lane g=2: c4-version
  const float h = fmaf(t2A, ovA, -ovA);           // ov * tanh(c)
  h4            = fmaf(t2B, ovB, -ovB);
  h0s = h;
  h1s = dppf<DPP_ROW_HALF_MIRROR>(h);   // lane^7  -> unit p^1
  h2s = dppf<DPP_ROW_ROR8>(h);          // lane^8  -> unit p^2
  h3s = dppf<DPP_ROW_MIRROR>(h);        // lane^15 -> unit p^3
}

template<int DD>
__device__ __forceinline__ void emit_row(unsigned char* ldsb, int dpA, int dpB,
    float h0s, float h1s, float h2s, float h3s, float h4) {
  if constexpr (DD) {
    uint2 pr; pr.x = pkrtz(h1s, h2s); pr.y = pkrtz(h3s, h4);
    *(uint2*)(ldsb + dpA + 64) = pr;                                  // C pair
    *(unsigned short*)(ldsb + dpB + 2) = (unsigned short)pkrtz(h0s, h0s); // B.hi
  } else {
    uint2 pr; pr.x = pkrtz(h0s, h1s); pr.y = pkrtz(h2s, h3s);
    *(uint2*)(ldsb + dpA) = pr;                                       // A pair
    *(unsigned short*)(ldsb + dpB) = (unsigned short)pkrtz(h4, h4);   // B.lo
  }
}

// LDS-input scan (layers 1..4), 8-slot software pipeline. Direction templated.
template<int DD, bool STORE>
__device__ __forceinline__ void scan_lds(unsigned char* ldsb, int pA, int pB,
    int dpA, int dpB, bool doStore, const WS& W, float vm, float va, bool csel4,
    float& c, float& c4, float& h0s, float& h1s, float& h2s, float& h3s, float& h4)
{
  constexpr int s = DD ? -SLOT : SLOT;
  Row5 p_[8]; Pre2 pre[8];
  #pragma unroll
  for (int k = 0; k < 8; ++k) { p_[k] = ld_row(ldsb, pA, pB); pA += s; pB += s; }
  #pragma unroll
  for (int k = 0; k < 8; ++k) pre[k] = proj_dual(p_[k], W);
  #pragma unroll
  for (int k = 0; k < 8; ++k) { p_[k] = ld_row(ldsb, pA, pB); pA += s; pB += s; }
  c = 0.f; c4 = 0.f; h0s = h1s = h2s = h3s = h4 = 0.f;
  for (int tt = 0; tt + 16 < T_; tt += 8) {
    #pragma unroll
    for (int j = 0; j < 8; ++j) {
      recur_dual(pre[j].a, pre[j].b, W, vm, va, csel4, c, c4, h0s, h1s, h2s, h3s, h4);
      if constexpr (STORE) {
        if (doStore) emit_row<DD>(ldsb, dpA, dpB, h0s, h1s, h2s, h3s, h4);
        dpA += s; dpB += s;
      }
      pre[j] = proj_dual(p_[j], W);
      p_[j] = ld_row(ldsb, pA, pB); pA += s; pB += s;
    }
  }
  #pragma unroll
  for (int j = 0; j < 8; ++j) {     // steps T-16..T-9, refill pre from last rows
    recur_dual(pre[j].a, pre[j].b, W, vm, va, csel4, c, c4, h0s, h1s, h2s, h3s, h4);
    if constexpr (STORE) {
      if (doStore) emit_row<DD>(ldsb, dpA, dpB, h0s, h1s, h2s, h3s, h4);
      dpA += s; dpB += s;
    }
    pre[j] = proj_dual(p_[j], W);
  }
  #pragma unroll
  for (int j = 0; j < 8; ++j) {     // steps T-8..T-1
    recur_dual(pre[j].a, pre[j].b, W, vm, va, csel4, c, c4, h0s, h1s, h2s, h3s, h4);
    if constexpr (STORE) {
      if (doStore) emit_row<DD>(ldsb, dpA, dpB, h0s, h1s, h2s, h3s, h4);
      dpA += s; dpB += s;
    }
  }
}

// Layer-0 scan: f32 global input (width 2), packed to f16 + dot2. 8-deep prefetch.
template<int DD>
__device__ __forceinline__ void scan0(const float* src, unsigned char* ldsb,
    int dpA, int dpB, bool doStore, const WS& W, float vm, float va, bool csel4)
{
  constexpr int sstep = DD ? -2 : 2;
  constexpr int s = DD ? -SLOT : SLOT;
  float2 p_[8]; Pre2 pre[8];
  #pragma unroll
  for (int k = 0; k < 8; ++k) p_[k] = *(const float2*)(src + k * sstep);
  #pragma unroll
  for (int k = 0; k < 8; ++k) {
    const unsigned xp = pkrtz(p_[k].x, p_[k].y);
    pre[k].a = fdot2(xp, W.wpA[0], W.bbA);
    pre[k].b = fdot2(xp, W.wpB[0], W.bbB);
  }
  #pragma unroll
  for (int k = 0; k < 8; ++k) p_[k] = *(const float2*)(src + (8 + k) * sstep);
  const float* lp = src + 16 * sstep;
  float c = 0.f, c4 = 0.f, h0s = 0.f, h1s = 0.f, h2s = 0.f, h3s = 0.f, h4 = 0.f;
  for (int tt = 0; tt + 16 < T_; tt += 8) {
    #pragma unroll
    for (int j = 0; j < 8; ++j) {
      recur_dual(pre[j].a, pre[j].b, W, vm, va, csel4, c, c4, h0s, h1s, h2s, h3s, h4);
      if (doStore) emit_row<DD>(ldsb, dpA, dpB, h0s, h1s, h2s, h3s, h4);
      dpA += s; dpB += s;
      const unsigned xp = pkrtz(p_[j].x, p_[j].y);
      pre[j].a = fdot2(xp, W.wpA[0], W.bbA);
      pre[j].b = fdot2(xp, W.wpB[0], W.bbB);
      p_[j] = *(const float2*)lp; lp += sstep;
    }
  }
  #pragma unroll
  for (int j = 0; j < 8; ++j) {
    recur_dual(pre[j].a, pre[j].b, W, vm, va, csel4, c, c4, h0s, h1s, h2s, h3s, h4);
    if (doStore) emit_row<DD>(ldsb, dpA, dpB, h0s, h1s, h2s, h3s, h4);
    dpA += s; dpB += s;
    const unsigned xp = pkrtz(p_[j].x, p_[j].y);
    pre[j].a = fdot2(xp, W.wpA[0], W.bbA);
    pre[j].b = fdot2(xp, W.wpB[0], W.bbB);
  }
  #pragma unroll
  for (int j = 0; j < 8; ++j) {
    recur_dual(pre[j].a, pre[j].b, W, vm, va, csel4, c, c4, h0s, h1s, h2s, h3s, h4);
    if (doStore) emit_row<DD>(ldsb, dpA, dpB, h0s, h1s, h2s, h3s, h4);
    dpA += s; dpB += s;
  }
}

__device__ __forceinline__ void load_rec(WS& W, const float* Whp, const float* bp,
    int rowA, int rowB, int p, int i1, int i2, int i3, float km) {
  W.wsA[0] = Whp[rowA*5+p]*km;  W.wsA[1] = Whp[rowA*5+i1]*km; W.wsA[2] = Whp[rowA*5+i2]*km;
  W.wsA[3] = Whp[rowA*5+i3]*km; W.wsA[4] = Whp[rowA*5+4]*km;
  W.wsB[0] = Whp[rowB*5+p]*km;  W.wsB[1] = Whp[rowB*5+i1]*km; W.wsB[2] = Whp[rowB*5+i2]*km;
  W.wsB[3] = Whp[rowB*5+i3]*km; W.wsB[4] = Whp[rowB*5+4]*km;
  W.bbA = bp[rowA]*km; W.bbB = bp[rowB]*km;
}

__global__ __launch_bounds__(256) void lstm_all(
    const float* __restrict__ x, const float* __restrict__ Wih0,
    const float* __restrict__ Wih, const float* __restrict__ Whh,
    const float* __restrict__ bias, const float* __restrict__ Wfc,
    const float* __restrict__ bfc, float* __restrict__ out)
{
  __shared__ __align__(16) unsigned char ldsb[163840];   // gfx950 LDS max

  const int tid  = threadIdx.x;
  const int lane = tid & 63;
  const int wave = tid >> 6;
  const int cw   = lane >> 4;          // chain within wave: 0..3
  const int sub  = lane & 15;
  const int p    = sub >> 2;           // hidden unit (quad) 0..3
  const int g    = sub & 3;            // gate 0=i,1=f,2=g,3=o
  const int rowA = g * 5 + p;
  const int rowB = g * 5 + 4;
  const int dd   = wave & 1;           // direction, WAVE-UNIFORM
  const int blb  = cw + (wave >> 1) * 4;   // block-local batch 0..7
  const int babs = blockIdx.x * NB_ + blb;

  const int i1 = p ^ 1, i2 = p ^ 2, i3 = p ^ 3;
  const bool csel4 = (g & 2) != 0;     // tanh lane-split selector

  const float LOG2E = 1.4426950408889634f;
  const float km = (g == 2) ? (-2.0f * LOG2E) : (-LOG2E);
  const float vm = (g == 2) ? 1.0f : 0.5f;
  const float va = (g == 2) ? -1.0f : 0.0f;

  const bool doStore = (sub == 0);
  const int t0 = dd ? (T_ - 1) : 0;
  const int slotA = blb * 8;
  const int slotB = 128 + blb * 4;

  WS W;
  float c, c4, h0s, h1s, h2s, h3s, h4;

  // ---------------- layer 0 (f32 x, width 2) -> buf0 ----------------
  {
    const float* W0 = Wih0 + (size_t)dd * 20 * 2;
    W.wpA[0] = pkrtz(W0[rowA*2+0]*km, W0[rowA*2+1]*km);
    W.wpB[0] = pkrtz(W0[rowB*2+0]*km, W0[rowB*2+1]*km);
    load_rec(W, Whh + (size_t)dd * 20 * 5, bias + (size_t)dd * 20,
             rowA, rowB, p, i1, i2, i3, km);
    const int dpA = t0 * SLOT + slotA;            // buf0
    const int dpB = t0 * SLOT + slotB;
    const float* src0 = x + ((size_t)babs * T_ + t0) * 2;
    if (dd == 0) scan0<0>(src0, ldsb, dpA, dpB, doStore, W, vm, va, csel4);
    else         scan0<1>(src0, ldsb, dpA, dpB, doStore, W, vm, va, csel4);
  }
  __syncthreads();

  // ---------------- layers 1..3 ----------------
  for (int l = 1; l < 4; ++l) {
    const float* Wip = Wih + ((size_t)(l - 1) * 2 + dd) * 20 * 10;
    #pragma unroll
    for (int k = 0; k < 5; ++k) {
      W.wpA[k] = pkrtz(Wip[rowA*10+2*k]*km, Wip[rowA*10+2*k+1]*km);
      W.wpB[k] = pkrtz(Wip[rowB*10+2*k]*km, Wip[rowB*10+2*k+1]*km);
    }
    load_rec(W, Whh + ((size_t)l * 2 + dd) * 20 * 5, bias + ((size_t)l * 2 + dd) * 20,
             rowA, rowB, p, i1, i2, i3, km);
    const int sbuf = (l + 1) & 1, dbuf = l & 1;           // L1:0->1 L2:1->0 L3:0->1
    const int pA  = sbuf * BUFOFF + t0 * SLOT + slotA;
    const int pB  = sbuf * BUFOFF + t0 * SLOT + slotB;
    const int dpA = dbuf * BUFOFF + t0 * SLOT + slotA;
    const int dpB = dbuf * BUFOFF + t0 * SLOT + slotB;
    if (dd == 0) scan_lds<0, true>(ldsb, pA, pB, dpA, dpB, doStore, W, vm, va, csel4,
                                   c, c4, h0s, h1s, h2s, h3s, h4);
    else         scan_lds<1, true>(ldsb, pA, pB, dpA, dpB, doStore, W, vm, va, csel4,
                                   c, c4, h0s, h1s, h2s, h3s, h4);
    __syncthreads();
  }

  // ---------------- layer 4 (reads buf1): fwd full scan, bwd 1 step ----------------
  {
    const float* Wip = Wih + ((size_t)3 * 2 + dd) * 20 * 10;
    #pragma unroll
    for (int k = 0; k < 5; ++k) {
      W.wpA[k] = pkrtz(Wip[rowA*10+2*k]*km, Wip[rowA*10+2*k+1]*km);
      W.wpB[k] = pkrtz(Wip[rowB*10+2*k]*km, Wip[rowB*10+2*k+1]*km);
    }
    load_rec(W, Whh + ((size_t)4 * 2 + dd) * 20 * 5, bias + ((size_t)4 * 2 + dd) * 20,
             rowA, rowB, p, i1, i2, i3, km);

    if (dd == 0) {
      const int pA = BUFOFF + slotA;                       // forward from t=0
      const int pB = BUFOFF + slotB;
      scan_lds<0, false>(ldsb, pA, pB, 0, 0, false, W, vm, va, csel4,
                         c, c4, h0s, h1s, h2s, h3s, h4);
    } else {
      const int pA = BUFOFF + (T_ - 1) * SLOT + slotA;
      const int pB = BUFOFF + (T_ - 1) * SLOT + slotB;
      Row5 r = ld_row(ldsb, pA, pB);
      Pre2 pr = proj_dual(r, W);
      c = 0.f; c4 = 0.f; h0s = h1s = h2s = h3s = h4 = 0.f;
      recur_dual(pr.a, pr.b, W, vm, va, csel4, c, c4, h0s, h1s, h2s, h3s, h4);
    }
  }
  // hlast overlays the dead buf0 head (80 floats = 320 B).
  {
    float* hl = (float*)ldsb;
    if (doStore) {
      const int base = (blb * 2 + dd) * 5;
      hl[base + 0] = h0s; hl[base + 1] = h1s; hl[base + 2] = h2s;
      hl[base + 3] = h3s; hl[base + 4] = h4;
    }
  }
  __syncthreads();

  // ---------------- fused FC: out[b] = hlast[b] @ Wfc^T + bfc ----------------
  if (tid < 16) {
    const int bl = tid >> 1, o = tid & 1;
    const float* hl = (const float*)ldsb;
    const int gb = blockIdx.x * NB_ + bl;
    float a = bfc[o];
    #pragma unroll
    for (int u = 0; u < 5; ++u) a = fmaf(hl[(bl*2+0)*5 + u], Wfc[o * 10 + u], a);
    #pragma unroll
    for (int u = 0; u < 5; ++u) a = fmaf(hl[(bl*2+1)*5 + u], Wfc[o * 10 + 5 + u], a);
    out[gb * 2 + o] = a;
  }
}

extern "C" void kernel_launch(void* const* d_in, const int* in_sizes, int n_in,
                              void* d_out, int out_size, void* d_ws, size_t ws_size,
                              hipStream_t stream) {
  (void)in_sizes; (void)n_in; (void)out_size; (void)d_ws; (void)ws_size;
  const float* x    = (const float*)d_in[0];
  const float* Wih0 = (const float*)d_in[1];
  const float* Wih  = (const float*)d_in[2];
  const float* Whh  = (const float*)d_in[3];
  const float* bias = (const float*)d_in[4];
  const float* Wfc  = (const float*)d_in[5];
  const float* bfc  = (const float*)d_in[6];
  float* out = (float*)d_out;

  dim3 grid(B_ / NB_);   // 256 blocks, 1 per CU
  dim3 block(256);
  lstm_all<<<grid, block, 0, stream>>>(x, Wih0, Wih, Whh, bias, Wfc, bfc, out);
}